// Round 3
// baseline (281.666 us; speedup 1.0000x reference)
//
#include <hip/hip_runtime.h>

#define B 4
#define S 2048
#define H 16
#define D 64
#define E 1024
#define BH (B*H)

typedef __bf16 bf16;
typedef __bf16 bf16x8 __attribute__((ext_vector_type(8)));
typedef __bf16 bf16x4 __attribute__((ext_vector_type(4)));
typedef __bf16 bf16x2 __attribute__((ext_vector_type(2)));
typedef float  f32x4  __attribute__((ext_vector_type(4)));
typedef float  f32x16 __attribute__((ext_vector_type(16)));

__device__ __forceinline__ f32x4 mfma16(bf16x8 a, bf16x8 b, f32x4 c) {
    return __builtin_amdgcn_mfma_f32_16x16x32_bf16(a, b, c, 0, 0, 0);
}
__device__ __forceinline__ f32x16 mfma32(bf16x8 a, bf16x8 b, f32x16 c) {
    return __builtin_amdgcn_mfma_f32_32x32x16_bf16(a, b, c, 0, 0, 0);
}

__device__ __forceinline__ unsigned pack2(float lo, float hi) {
    union { bf16x2 v; unsigned u; } x;
    x.v[0] = (bf16)lo; x.v[1] = (bf16)hi;
    return x.u;
}
__device__ __forceinline__ bf16x8 frag4(unsigned a0, unsigned a1, unsigned a2, unsigned a3) {
    union { unsigned u[4]; bf16x8 v; } x;
    x.u[0] = a0; x.u[1] = a1; x.u[2] = a2; x.u[3] = a3;
    return x.v;
}

#define SCALE 0.04508422002778f   // (1/sqrt(1024)) * log2(e), folded into Q

// ---------------------------------------------------------------------------
// Kernel 1: QKV projection (R3 structure) + fused Wo fp32->bf16 (type 3).
// UNCHANGED this round (no counters for it yet).
// ---------------------------------------------------------------------------
__global__ __launch_bounds__(256) void proj_kernel(
    const float* __restrict__ values, const float* __restrict__ keys,
    const float* __restrict__ query,  const float* __restrict__ Wv,
    const float* __restrict__ Wk,     const float* __restrict__ Wq,
    const float* __restrict__ Wo,
    bf16* __restrict__ qp, bf16* __restrict__ kp, bf16* __restrict__ vt,
    bf16* __restrict__ wb)
{
    const int t    = threadIdx.x;
    const int bh   = blockIdx.y;
    const int type = blockIdx.z;

    if (type == 3) {
        int idx = (bh * 16 + blockIdx.x) * 1024 + t * 4;
        f32x4 v = *(const f32x4*)(Wo + idx);
        *(bf16x4*)(wb + idx) = __builtin_convertvector(v, bf16x4);
        return;
    }

    const int b = bh >> 4, h = bh & 15;
    const int s0 = blockIdx.x * 128;
    const int w = t >> 6, lane = t & 63;
    const int m = lane & 15, g = lane >> 4;
    const int row0 = s0 + w * 32;

    const float* X = (type == 0) ? query : (type == 1) ? keys : values;
    const float* W = (type == 0) ? Wq    : (type == 1) ? Wk   : Wv;

    bf16x8 xa[2][2];
    #pragma unroll
    for (int mt = 0; mt < 2; ++mt)
        #pragma unroll
        for (int kb = 0; kb < 2; ++kb) {
            const float* px = X + (size_t)(b * S + row0 + mt * 16 + m) * E + h * D + kb * 32 + g * 8;
            f32x4 lo = *(const f32x4*)px;
            f32x4 hi = *(const f32x4*)(px + 4);
            if (type == 0) { lo *= SCALE; hi *= SCALE; }
            bf16x8 f;
            #pragma unroll
            for (int i = 0; i < 4; ++i) { f[i] = (bf16)lo[i]; f[4 + i] = (bf16)hi[i]; }
            xa[mt][kb] = f;
        }

    bf16x8 wf[4][2];
    #pragma unroll
    for (int nt = 0; nt < 4; ++nt)
        #pragma unroll
        for (int kb = 0; kb < 2; ++kb) {
            const float* pw = W + (nt * 16 + m) * 64 + kb * 32 + g * 8;
            f32x4 lo = *(const f32x4*)pw;
            f32x4 hi = *(const f32x4*)(pw + 4);
            bf16x8 f;
            #pragma unroll
            for (int i = 0; i < 4; ++i) { f[i] = (bf16)lo[i]; f[4 + i] = (bf16)hi[i]; }
            wf[nt][kb] = f;
        }

    if (type == 2) {
        #pragma unroll
        for (int mt = 0; mt < 2; ++mt)
            #pragma unroll
            for (int nt = 0; nt < 4; ++nt) {
                f32x4 acc = (f32x4){0.f, 0.f, 0.f, 0.f};
                acc = mfma16(xa[mt][0], wf[nt][0], acc);
                acc = mfma16(xa[mt][1], wf[nt][1], acc);
                bf16x4 pk = __builtin_convertvector(acc, bf16x4);
                *(bf16x4*)(vt + (size_t)(bh * D + nt * 16 + m) * S + row0 + mt * 16 + g * 4) = pk;
            }
    } else {
        bf16* out = (type == 0) ? qp : kp;
        #pragma unroll
        for (int mt = 0; mt < 2; ++mt)
            #pragma unroll
            for (int nt = 0; nt < 4; ++nt) {
                f32x4 acc = (f32x4){0.f, 0.f, 0.f, 0.f};
                acc = mfma16(wf[nt][0], xa[mt][0], acc);
                acc = mfma16(wf[nt][1], xa[mt][1], acc);
                bf16x4 pk = __builtin_convertvector(acc, bf16x4);
                *(bf16x4*)(out + (size_t)(bh * S + row0 + mt * 16 + m) * D + nt * 16 + g * 4) = pk;
            }
    }
}

// ---------------------------------------------------------------------------
// Kernel 2: flash attention — R5 restructure: 32x32x16 MFMAs, 64 q-rows/wave,
// 256 q/block, P kept in registers (cvt_pk + shfl_xor(32) exchange), in-lane L.
// Eliminates the P LDS round-trip (32KB/block-iter) that made the previous
// structure LDS-pipe-bound (LDS 3500 cyc vs MFMA 2794 cyc per CU-iter, +24us
// of SQ_LDS_BANK_CONFLICT). New balance: LDS ~1250 vs MFMA ~2066 cyc -> MFMA-bound.
//
// Layouts (32x32x16 bf16):
//   A: lane holds A[row=l&31][k=(l>>5)*8+j]   (mirror of verified 16x16x32)
//   B: lane holds B[col=l&31][k=(l>>5)*8+j]
//   C/D: col=l&31, row=(reg&3)+8*(reg>>2)+4*(l>>5)   [m74/m101 verified]
// QK: E^T = mfma(K, Q): rows=key-slots, cols=q. Lane holds 16 key-slots for
// q=l&31. Pack pairs -> 8 dwords (own[c] holds keys {(2c&3)+8*(c>>1)+4*h5,+1}).
// shfl_xor(32) fills the complementary half; PV A-frag for k-block kap is
//   h==0: [own[4k],own[4k+1],part[4k],part[4k+1]]
//   h==1: [part[4k+2],part[4k+3],own[4k+2],own[4k+3]]
// ---------------------------------------------------------------------------
__global__ __launch_bounds__(256, 2) void attn_kernel(
    const bf16* __restrict__ qp, const bf16* __restrict__ kp,
    const bf16* __restrict__ vt, bf16* __restrict__ attn)
{
    const int t  = threadIdx.x;
    const int bh = blockIdx.y;
    const int b  = bh >> 4, h = bh & 15;
    const int q0 = blockIdx.x * 256;
    const int w  = t >> 6, lane = t & 63;
    const int l31 = lane & 31, h5 = lane >> 5;

    __shared__ bf16 Ks[64 * 72];   // [key][d], row stride 72 elems (144B)
    __shared__ bf16 Vs[64 * 72];   // [d][key]

    // Q fragments: B operand, 2 q-blocks x 4 d-kblocks
    bf16x8 qa[2][4];
    #pragma unroll
    for (int qb = 0; qb < 2; ++qb)
        #pragma unroll
        for (int kb = 0; kb < 4; ++kb)
            qa[qb][kb] = *(const bf16x8*)(qp + (size_t)(bh * S + q0 + w * 64 + qb * 32 + l31) * D + kb * 16 + h5 * 8);

    f32x16 O[2][2];                // [qb][db]
    #pragma unroll
    for (int qb = 0; qb < 2; ++qb)
        #pragma unroll
        for (int db = 0; db < 2; ++db)
            #pragma unroll
            for (int i = 0; i < 16; ++i) O[qb][db][i] = 0.f;
    float Lacc[2] = {0.f, 0.f};

    // register prefetch of tile kt=0 (K and V, 64x64 bf16 each)
    bf16x8 kreg[2], vreg[2];
    #pragma unroll
    for (int p = 0; p < 2; ++p) {
        int id = p * 256 + t;
        int row = id >> 3, ch = (id & 7) * 8;
        kreg[p] = *(const bf16x8*)(kp + (size_t)(bh * S + row) * D + ch);
        vreg[p] = *(const bf16x8*)(vt + (size_t)(bh * D + row) * S + ch);
    }

    for (int kt = 0; kt < S / 64; ++kt) {
        __syncthreads();
        #pragma unroll
        for (int p = 0; p < 2; ++p) {
            int id = p * 256 + t;
            int row = id >> 3, ch = (id & 7) * 8;
            *(bf16x8*)(Ks + row * 72 + ch) = kreg[p];
            *(bf16x8*)(Vs + row * 72 + ch) = vreg[p];
        }
        __syncthreads();

        if (kt < S / 64 - 1) {
            #pragma unroll
            for (int p = 0; p < 2; ++p) {
                int id = p * 256 + t;
                int row = id >> 3, ch = (id & 7) * 8;
                kreg[p] = *(const bf16x8*)(kp + (size_t)(bh * S + (kt + 1) * 64 + row) * D + ch);
                vreg[p] = *(const bf16x8*)(vt + (size_t)(bh * D + row) * S + (kt + 1) * 64 + ch);
            }
        }

        #pragma unroll
        for (int kg = 0; kg < 2; ++kg) {
            // ---- QK: E^T[key-slot][q] for 32 keys x 64 q ----
            f32x16 e[2];
            #pragma unroll
            for (int qb = 0; qb < 2; ++qb)
                #pragma unroll
                for (int i = 0; i < 16; ++i) e[qb][i] = 0.f;
            #pragma unroll
            for (int kb = 0; kb < 4; ++kb) {
                bf16x8 kf = *(const bf16x8*)(Ks + (kg * 32 + l31) * 72 + kb * 16 + h5 * 8);
                e[0] = mfma32(kf, qa[0][kb], e[0]);
                e[1] = mfma32(kf, qa[1][kb], e[1]);
            }

            // ---- V fragments for this key-group (shared across qb) ----
            bf16x8 vf[2][2];   // [kap][db]
            #pragma unroll
            for (int kap = 0; kap < 2; ++kap)
                #pragma unroll
                for (int db = 0; db < 2; ++db)
                    vf[kap][db] = *(const bf16x8*)(Vs + (db * 32 + l31) * 72 + kg * 32 + kap * 16 + h5 * 8);

            // ---- exp2, pack, in-register exchange, PV ----
            #pragma unroll
            for (int qb = 0; qb < 2; ++qb) {
                unsigned own[8];
                float ls = 0.f;
                #pragma unroll
                for (int c = 0; c < 8; ++c) {
                    float lo = __builtin_amdgcn_exp2f(e[qb][2 * c]);
                    float hi = __builtin_amdgcn_exp2f(e[qb][2 * c + 1]);
                    ls += lo + hi;
                    own[c] = pack2(lo, hi);
                }
                Lacc[qb] += ls;
                unsigned part[8];
                #pragma unroll
                for (int c = 0; c < 8; ++c) part[c] = __shfl_xor(own[c], 32, 64);
                #pragma unroll
                for (int kap = 0; kap < 2; ++kap) {
                    unsigned a0 = h5 ? part[4 * kap + 2] : own[4 * kap];
                    unsigned a1 = h5 ? part[4 * kap + 3] : own[4 * kap + 1];
                    unsigned a2 = h5 ? own[4 * kap + 2]  : part[4 * kap];
                    unsigned a3 = h5 ? own[4 * kap + 3]  : part[4 * kap + 1];
                    bf16x8 pf = frag4(a0, a1, a2, a3);
                    O[qb][0] = mfma32(pf, vf[kap][0], O[qb][0]);
                    O[qb][1] = mfma32(pf, vf[kap][1], O[qb][1]);
                }
            }
        }
    }

    // ---- epilogue: L combine across halves, redistribute 1/L to O layout ----
    #pragma unroll
    for (int qb = 0; qb < 2; ++qb) {
        float Ls = Lacc[qb] + __shfl_xor(Lacc[qb], 32, 64);
        float li = 1.f / Ls;
        #pragma unroll
        for (int r = 0; r < 16; ++r) {
            int crow = (r & 3) + 8 * (r >> 2) + 4 * h5;
            float lr = __shfl(li, crow | (lane & 32), 64);
            int qg = q0 + w * 64 + qb * 32 + crow;
            #pragma unroll
            for (int db = 0; db < 2; ++db)
                attn[(size_t)(b * S + qg) * E + h * D + db * 32 + l31] =
                    (bf16)(O[qb][db][r] * lr);
        }
    }
}

// ---------------------------------------------------------------------------
// Kernel 3: out = attn @ Wo^T + bo. UNCHANGED this round.
// ---------------------------------------------------------------------------
__global__ __launch_bounds__(256, 4) void out_gemm(
    const bf16* __restrict__ A, const bf16* __restrict__ wo,
    const float* __restrict__ bo, float* __restrict__ out)
{
    const int t  = threadIdx.x;
    const int n0 = blockIdx.x * 64;
    const int m0 = blockIdx.y * 128;
    const int w  = t >> 6, lane = t & 63;
    const int m  = lane & 15, g = lane >> 4;
    const int wm = w >> 1, wn = w & 1;

    __shared__ bf16 As[128 * 72];
    __shared__ bf16 Bs[64 * 72];

    f32x4 acc[4][2];
    #pragma unroll
    for (int mt = 0; mt < 4; ++mt)
        #pragma unroll
        for (int nt = 0; nt < 2; ++nt) acc[mt][nt] = (f32x4){0.f, 0.f, 0.f, 0.f};

    bf16x8 pA[4], pB[2];
    #pragma unroll
    for (int p = 0; p < 4; ++p) {
        int id = p * 256 + t;
        pA[p] = *(const bf16x8*)(A + (size_t)(m0 + (id >> 3)) * E + (id & 7) * 8);
    }
    #pragma unroll
    for (int p = 0; p < 2; ++p) {
        int id = p * 256 + t;
        pB[p] = *(const bf16x8*)(wo + (size_t)(n0 + (id >> 3)) * E + (id & 7) * 8);
    }

    for (int kt = 0; kt < E / 64; ++kt) {
        __syncthreads();
        #pragma unroll
        for (int p = 0; p < 4; ++p) {
            int id = p * 256 + t;
            *(bf16x8*)(As + (id >> 3) * 72 + (id & 7) * 8) = pA[p];
        }
        #pragma unroll
        for (int p = 0; p < 2; ++p) {
            int id = p * 256 + t;
            *(bf16x8*)(Bs + (id >> 3) * 72 + (id & 7) * 8) = pB[p];
        }
        __syncthreads();
        if (kt + 1 < E / 64) {
            #pragma unroll
            for (int p = 0; p < 4; ++p) {
                int id = p * 256 + t;
                pA[p] = *(const bf16x8*)(A + (size_t)(m0 + (id >> 3)) * E + (kt + 1) * 64 + (id & 7) * 8);
            }
            #pragma unroll
            for (int p = 0; p < 2; ++p) {
                int id = p * 256 + t;
                pB[p] = *(const bf16x8*)(wo + (size_t)(n0 + (id >> 3)) * E + (kt + 1) * 64 + (id & 7) * 8);
            }
        }

        #pragma unroll
        for (int kb = 0; kb < 2; ++kb) {
            bf16x8 af[4], bfr[2];
            #pragma unroll
            for (int mt = 0; mt < 4; ++mt)
                af[mt] = *(const bf16x8*)(As + (wm * 64 + mt * 16 + m) * 72 + kb * 32 + g * 8);
            #pragma unroll
            for (int nt = 0; nt < 2; ++nt)
                bfr[nt] = *(const bf16x8*)(Bs + (wn * 32 + nt * 16 + m) * 72 + kb * 32 + g * 8);
            #pragma unroll
            for (int mt = 0; mt < 4; ++mt)
                #pragma unroll
                for (int nt = 0; nt < 2; ++nt)
                    acc[mt][nt] = mfma16(bfr[nt], af[mt], acc[mt][nt]);
        }
    }

    #pragma unroll
    for (int mt = 0; mt < 4; ++mt)
        #pragma unroll
        for (int nt = 0; nt < 2; ++nt) {
            f32x4 bias = *(const f32x4*)(bo + n0 + wn * 32 + nt * 16 + g * 4);
            f32x4 res = acc[mt][nt] + bias;
            *(f32x4*)(out + (size_t)(m0 + wm * 64 + mt * 16 + m) * E + n0 + wn * 32 + nt * 16 + g * 4) = res;
        }
}

// ---------------------------------------------------------------------------
extern "C" void kernel_launch(void* const* d_in, const int* in_sizes, int n_in,
                              void* d_out, int out_size, void* d_ws, size_t ws_size,
                              hipStream_t stream) {
    const float* values = (const float*)d_in[0];
    const float* keys   = (const float*)d_in[1];
    const float* query  = (const float*)d_in[2];
    const float* Wv     = (const float*)d_in[3];
    const float* Wk     = (const float*)d_in[4];
    const float* Wq     = (const float*)d_in[5];
    const float* Wo     = (const float*)d_in[6];
    const float* bo     = (const float*)d_in[7];
    float* out = (float*)d_out;

    bf16* qp   = (bf16*)d_ws;
    bf16* kp   = qp  + (size_t)BH * S * D;
    bf16* vt   = kp  + (size_t)BH * S * D;
    bf16* attn = vt  + (size_t)BH * S * D;
    bf16* wb   = attn + (size_t)BH * S * D;   // 2 MB for bf16 Wo

    proj_kernel<<<dim3(S / 128, BH, 4), 256, 0, stream>>>(
        values, keys, query, Wv, Wk, Wq, Wo, qp, kp, vt, wb);
    attn_kernel<<<dim3(S / 256, BH), 256, 0, stream>>>(qp, kp, vt, attn);
    out_gemm<<<dim3(E / 64, (B * S) / 128), 256, 0, stream>>>(attn, wb, bo, out);
}